// Round 8
// baseline (497.303 us; speedup 1.0000x reference)
//
#include <hip/hip_runtime.h>
#include <hip/hip_fp16.h>

#define N_NODES 50000
#define E_EDGES 800000
#define ETOT (E_EDGES + N_NODES)   // self-loops appended
#define IN_CH 128
#define HH 128                     // HEADS*HID
#define HEADS 4
#define HID 32
#define OUT_CH 32
#define NEG 0.2f

#define GEMM_BLOCKS ((N_NODES + 127) / 128)   // 391
#define FILL_BLOCKS ((ETOT + 1023) / 1024)    // 831
#define XP 132                                // padded LDS row stride

// ===== fused: [blocks 0..390] xw1 = x@W1 + att dots ; [391..] edge-rank atomic pass =====
__global__ __launch_bounds__(256, 2) void gemm1_fused(const float* __restrict__ x,
                                                      const float* __restrict__ W1,
                                                      const float* __restrict__ att_s,
                                                      const float* __restrict__ att_d,
                                                      const int* __restrict__ ei,
                                                      __half* __restrict__ xwh,
                                                      float* __restrict__ a1s,
                                                      float* __restrict__ a1d,
                                                      int* __restrict__ deg,
                                                      int* __restrict__ idx) {
    __shared__ float Xs[32][XP];
    __shared__ float Ws[32][XP];
    int t = threadIdx.x;

    if (blockIdx.x >= GEMM_BLOCKS) {
        // ---------- edge-rank pass: idx[e] = rank of e within its dst group ----------
        int base = (blockIdx.x - GEMM_BLOCKS) * 1024 + t;
#pragma unroll
        for (int q = 0; q < 4; ++q) {
            int e = base + q * 256;
            if (e < ETOT) {
                int d = (e < E_EDGES) ? ei[E_EDGES + e] : e - E_EDGES;
                idx[e] = atomicAdd(deg + d, 1);
            }
        }
        return;
    }

    // ---------- GEMM part: 128x128 tile, BK=32, 8x8 micro-tile ----------
    int tx = t & 15, ty = t >> 4;
    int row0 = blockIdx.x * 128;
    float acc[8][8] = {};

    for (int k0 = 0; k0 < IN_CH; k0 += 32) {
#pragma unroll
        for (int p = 0; p < 4; ++p) {
            int i2 = t + p * 256;
            int kk = i2 >> 5, c4 = i2 & 31;
            float4 v = *(const float4*)&W1[(size_t)(k0 + kk) * HH + c4 * 4];
            *(float4*)&Ws[kk][c4 * 4] = v;
        }
#pragma unroll
        for (int p = 0; p < 4; ++p) {
            int i2 = t + p * 256;
            int rr = i2 >> 3, c4 = i2 & 7;
            int row = row0 + rr;
            float4 v = make_float4(0.f, 0.f, 0.f, 0.f);
            if (row < N_NODES) v = *(const float4*)&x[(size_t)row * IN_CH + k0 + c4 * 4];
            Xs[c4 * 4 + 0][rr] = v.x;
            Xs[c4 * 4 + 1][rr] = v.y;
            Xs[c4 * 4 + 2][rr] = v.z;
            Xs[c4 * 4 + 3][rr] = v.w;
        }
        __syncthreads();
#pragma unroll 8
        for (int kk = 0; kk < 32; ++kk) {
            float4 xa0 = *(const float4*)&Xs[kk][ty * 4];
            float4 xa1 = *(const float4*)&Xs[kk][ty * 4 + 64];
            float4 wb0 = *(const float4*)&Ws[kk][tx * 4];
            float4 wb1 = *(const float4*)&Ws[kk][tx * 4 + 64];
            float xa[8] = {xa0.x, xa0.y, xa0.z, xa0.w, xa1.x, xa1.y, xa1.z, xa1.w};
            float wb[8] = {wb0.x, wb0.y, wb0.z, wb0.w, wb1.x, wb1.y, wb1.z, wb1.w};
#pragma unroll
            for (int i = 0; i < 8; ++i)
#pragma unroll
                for (int j = 0; j < 8; ++j)
                    acc[i][j] = fmaf(xa[i], wb[j], acc[i][j]);
        }
        __syncthreads();
    }

    float asr[8], adr[8];
#pragma unroll
    for (int j = 0; j < 8; ++j) {
        int col = tx * 4 + (j & 3) + ((j >> 2) << 6);
        asr[j] = att_s[col];
        adr[j] = att_d[col];
    }
    int hA = tx >> 3;

#pragma unroll
    for (int i = 0; i < 8; ++i) {
        int row = row0 + ty * 4 + (i < 4 ? i : 60 + i);
        if (row < N_NODES) {
            union { __half2 h2; unsigned u; } c0, c1, c2, c3;
            c0.h2 = __floats2half2_rn(acc[i][0], acc[i][1]);
            c1.h2 = __floats2half2_rn(acc[i][2], acc[i][3]);
            c2.h2 = __floats2half2_rn(acc[i][4], acc[i][5]);
            c3.h2 = __floats2half2_rn(acc[i][6], acc[i][7]);
            *(uint2*)&xwh[(size_t)row * HH + tx * 4]      = make_uint2(c0.u, c1.u);
            *(uint2*)&xwh[(size_t)row * HH + tx * 4 + 64] = make_uint2(c2.u, c3.u);
        }
        float psA = 0.f, pdA = 0.f, psB = 0.f, pdB = 0.f;
#pragma unroll
        for (int j = 0; j < 4; ++j) {
            psA = fmaf(acc[i][j], asr[j], psA);
            pdA = fmaf(acc[i][j], adr[j], pdA);
            psB = fmaf(acc[i][j + 4], asr[j + 4], psB);
            pdB = fmaf(acc[i][j + 4], adr[j + 4], pdB);
        }
#pragma unroll
        for (int off = 1; off < 8; off <<= 1) {
            psA += __shfl_xor(psA, off, 16);
            pdA += __shfl_xor(pdA, off, 16);
            psB += __shfl_xor(psB, off, 16);
            pdB += __shfl_xor(pdB, off, 16);
        }
        if ((tx & 7) == 0 && row < N_NODES) {
            a1s[row * 4 + hA]     = psA;
            a1d[row * 4 + hA]     = pdA;
            a1s[row * 4 + hA + 2] = psB;
            a1d[row * 4 + hA + 2] = pdB;
        }
    }
}

// ================= scan (rowptr from deg) =================
__device__ __forceinline__ int block_incl_scan(int v, int t) {
    for (int off = 1; off < 64; off <<= 1) {
        int n = __shfl_up(v, off, 64);
        if ((t & 63) >= off) v += n;
    }
    __shared__ int wsum[4];
    if ((t & 63) == 63) wsum[t >> 6] = v;
    __syncthreads();
    int w = t >> 6;
    if (w > 0) {
        int add = 0;
        for (int k = 0; k < w; ++k) add += wsum[k];
        v += add;
    }
    __syncthreads();
    return v;
}

#define NCHUNK ((N_NODES + 255) / 256)   // 196

__global__ void scan_s1(const int* __restrict__ deg, int* __restrict__ rowptr,
                        int* __restrict__ partials) {
    int t = threadIdx.x;
    int i = blockIdx.x * 256 + t;
    int v = (i < N_NODES) ? deg[i] : 0;
    int s = block_incl_scan(v, t);
    if (i < N_NODES) rowptr[i + 1] = s;
    if (t == 255) partials[blockIdx.x] = s;
}

__global__ void scan_s2(int* __restrict__ partials) {
    int t = threadIdx.x;
    int v = (t < NCHUNK) ? partials[t] : 0;
    int s = block_incl_scan(v, t);
    if (t < NCHUNK) partials[t] = s;
}

__global__ void scan_s3(int* __restrict__ rowptr, const int* __restrict__ partials) {
    int i = blockIdx.x * blockDim.x + threadIdx.x;
    if (i == 0) rowptr[0] = 0;
    if (i < N_NODES) {
        int c = i >> 8;
        if (c > 0) rowptr[i + 1] += partials[c - 1];
    }
}

// ================= place: csr_src[rowptr[d]+idx[e]] = s (no atomics) =================
__global__ void place_csr(const int* __restrict__ ei, const int* __restrict__ idx,
                          const int* __restrict__ rowptr, int* __restrict__ csr_src) {
    int e = blockIdx.x * blockDim.x + threadIdx.x;
    if (e >= ETOT) return;
    int s, d;
    if (e < E_EDGES) { s = ei[e]; d = ei[E_EDGES + e]; }
    else { s = e - E_EDGES; d = s; }
    csr_src[rowptr[d] + idx[e]] = s;
}

// ========== layer-1 gather-aggregate, fused denominator, 4-edge ILP ==========
__global__ void gather1(const int* __restrict__ rowptr, const int* __restrict__ csr_src,
                        const float* __restrict__ a1s, const float* __restrict__ a1d,
                        const __half* __restrict__ xwh, float* __restrict__ agg) {
    int t = threadIdx.x;
    int d = blockIdx.x * 4 + (t >> 6);   // one 64-lane wave per node
    if (d >= N_NODES) return;
    int l = t & 63;                       // channels 2l, 2l+1; head = l>>4
    int h = l >> 4;
    float ad = a1d[d * 4 + h];
    int p0 = rowptr[d], p1 = rowptr[d + 1];
    float acc0 = 0.f, acc1 = 0.f, wsum = 0.f;
    int p = p0;
    for (; p + 3 < p1; p += 4) {
        int s0 = csr_src[p], s1 = csr_src[p + 1], s2 = csr_src[p + 2], s3 = csr_src[p + 3];
        float v0 = a1s[s0 * 4 + h] + ad; v0 = v0 > 0.f ? v0 : NEG * v0;
        float v1 = a1s[s1 * 4 + h] + ad; v1 = v1 > 0.f ? v1 : NEG * v1;
        float v2 = a1s[s2 * 4 + h] + ad; v2 = v2 > 0.f ? v2 : NEG * v2;
        float v3 = a1s[s3 * 4 + h] + ad; v3 = v3 > 0.f ? v3 : NEG * v3;
        float w0 = __expf(v0), w1 = __expf(v1), w2 = __expf(v2), w3 = __expf(v3);
        float2 f0 = __half22float2(*(const __half2*)&xwh[(size_t)s0 * HH + 2 * l]);
        float2 f1 = __half22float2(*(const __half2*)&xwh[(size_t)s1 * HH + 2 * l]);
        float2 f2 = __half22float2(*(const __half2*)&xwh[(size_t)s2 * HH + 2 * l]);
        float2 f3 = __half22float2(*(const __half2*)&xwh[(size_t)s3 * HH + 2 * l]);
        acc0 = fmaf(w0, f0.x, acc0); acc1 = fmaf(w0, f0.y, acc1);
        acc0 = fmaf(w1, f1.x, acc0); acc1 = fmaf(w1, f1.y, acc1);
        acc0 = fmaf(w2, f2.x, acc0); acc1 = fmaf(w2, f2.y, acc1);
        acc0 = fmaf(w3, f3.x, acc0); acc1 = fmaf(w3, f3.y, acc1);
        wsum += (w0 + w1) + (w2 + w3);
    }
    for (; p < p1; ++p) {
        int s = csr_src[p];
        float v = a1s[s * 4 + h] + ad; v = v > 0.f ? v : NEG * v;
        float w = __expf(v);
        float2 f = __half22float2(*(const __half2*)&xwh[(size_t)s * HH + 2 * l]);
        acc0 = fmaf(w, f.x, acc0); acc1 = fmaf(w, f.y, acc1);
        wsum += w;
    }
    float r = 1.f / (wsum + 1e-16f);
    *(float2*)&agg[(size_t)d * HH + 2 * l] = make_float2(acc0 * r, acc1 * r);
}

// ====== layer-2 GEMM (tiled): h = elu(agg+b1); hw2 = h @ W2 (fp16), + att dots ======
// 32 rows/block, 256 threads; thread = (rg = t>>5 -> rows rg*4..rg*4+3, col = t&31)
#define HP 132
__global__ void gemm2_tiled(const float* __restrict__ agg1,
                            const float* __restrict__ b1,
                            const float* __restrict__ W2,
                            const float* __restrict__ att_s,
                            const float* __restrict__ att_d,
                            __half* __restrict__ hw2h,
                            float* __restrict__ a2s,
                            float* __restrict__ a2d) {
    __shared__ float Wl[HH * OUT_CH];   // [k*32+col], 16 KiB
    __shared__ float hs[32][HP];        // elu(h) tile, 16.9 KiB
    int t = threadIdx.x;
    int row0 = blockIdx.x * 32;

    for (int i = t; i < HH * OUT_CH; i += 256) Wl[i] = W2[i];
    for (int i = t; i < 32 * 32; i += 256) {          // 32 rows x 32 float4
        int rr = i >> 5, c4 = i & 31;
        int row = row0 + rr;
        float4 v = make_float4(0.f, 0.f, 0.f, 0.f);
        if (row < N_NODES) v = *(const float4*)&agg1[(size_t)row * HH + c4 * 4];
        const float4 bv = *(const float4*)&b1[c4 * 4];
        v.x += bv.x; v.y += bv.y; v.z += bv.z; v.w += bv.w;
        v.x = v.x > 0.f ? v.x : (__expf(v.x) - 1.f);
        v.y = v.y > 0.f ? v.y : (__expf(v.y) - 1.f);
        v.z = v.z > 0.f ? v.z : (__expf(v.z) - 1.f);
        v.w = v.w > 0.f ? v.w : (__expf(v.w) - 1.f);
        *(float4*)&hs[rr][c4 * 4] = v;
    }
    __syncthreads();

    int rg = t >> 5, col = t & 31;
    int r0 = rg * 4;
    float acc[4] = {};
#pragma unroll
    for (int k0 = 0; k0 < HH; k0 += 4) {
        float4 h0 = *(const float4*)&hs[r0 + 0][k0];
        float4 h1 = *(const float4*)&hs[r0 + 1][k0];
        float4 h2 = *(const float4*)&hs[r0 + 2][k0];
        float4 h3 = *(const float4*)&hs[r0 + 3][k0];
        float w0 = Wl[(k0 + 0) * 32 + col];
        float w1 = Wl[(k0 + 1) * 32 + col];
        float w2 = Wl[(k0 + 2) * 32 + col];
        float w3 = Wl[(k0 + 3) * 32 + col];
        acc[0] = fmaf(h0.x, w0, acc[0]); acc[0] = fmaf(h0.y, w1, acc[0]);
        acc[0] = fmaf(h0.z, w2, acc[0]); acc[0] = fmaf(h0.w, w3, acc[0]);
        acc[1] = fmaf(h1.x, w0, acc[1]); acc[1] = fmaf(h1.y, w1, acc[1]);
        acc[1] = fmaf(h1.z, w2, acc[1]); acc[1] = fmaf(h1.w, w3, acc[1]);
        acc[2] = fmaf(h2.x, w0, acc[2]); acc[2] = fmaf(h2.y, w1, acc[2]);
        acc[2] = fmaf(h2.z, w2, acc[2]); acc[2] = fmaf(h2.w, w3, acc[2]);
        acc[3] = fmaf(h3.x, w0, acc[3]); acc[3] = fmaf(h3.y, w1, acc[3]);
        acc[3] = fmaf(h3.z, w2, acc[3]); acc[3] = fmaf(h3.w, w3, acc[3]);
    }

    float asc = att_s[col], adc = att_d[col];
    float ps[4], pd[4];
#pragma unroll
    for (int i = 0; i < 4; ++i) {
        int row = row0 + r0 + i;
        if (row < N_NODES) hw2h[(size_t)row * OUT_CH + col] = __float2half_rn(acc[i]);
        ps[i] = acc[i] * asc;
        pd[i] = acc[i] * adc;
    }
#pragma unroll
    for (int off = 1; off < 32; off <<= 1) {
#pragma unroll
        for (int i = 0; i < 4; ++i) {
            ps[i] += __shfl_xor(ps[i], off, 32);
            pd[i] += __shfl_xor(pd[i], off, 32);
        }
    }
    if (col == 0) {
#pragma unroll
        for (int i = 0; i < 4; ++i) {
            int row = row0 + r0 + i;
            if (row < N_NODES) { a2s[row] = ps[i]; a2d[row] = pd[i]; }
        }
    }
}

// ========== layer-2 gather-aggregate, fused denominator, 4-edge ILP ==========
__global__ void gather2(const int* __restrict__ rowptr, const int* __restrict__ csr_src,
                        const float* __restrict__ a2s, const float* __restrict__ a2d,
                        const __half* __restrict__ hw2h, const float* __restrict__ b2,
                        float* __restrict__ out) {
    int t = threadIdx.x;
    int d = blockIdx.x * 8 + (t >> 5);   // 32 lanes per node
    if (d >= N_NODES) return;
    int o = t & 31;
    float ad = a2d[d];
    int p0 = rowptr[d], p1 = rowptr[d + 1];
    float acc = 0.f, wsum = 0.f;
    int p = p0;
    for (; p + 3 < p1; p += 4) {
        int s0 = csr_src[p], s1 = csr_src[p + 1], s2 = csr_src[p + 2], s3 = csr_src[p + 3];
        float v0 = a2s[s0] + ad; v0 = v0 > 0.f ? v0 : NEG * v0;
        float v1 = a2s[s1] + ad; v1 = v1 > 0.f ? v1 : NEG * v1;
        float v2 = a2s[s2] + ad; v2 = v2 > 0.f ? v2 : NEG * v2;
        float v3 = a2s[s3] + ad; v3 = v3 > 0.f ? v3 : NEG * v3;
        float w0 = __expf(v0), w1 = __expf(v1), w2 = __expf(v2), w3 = __expf(v3);
        float x0 = __half2float(hw2h[(size_t)s0 * OUT_CH + o]);
        float x1 = __half2float(hw2h[(size_t)s1 * OUT_CH + o]);
        float x2 = __half2float(hw2h[(size_t)s2 * OUT_CH + o]);
        float x3 = __half2float(hw2h[(size_t)s3 * OUT_CH + o]);
        acc = fmaf(w0, x0, acc); acc = fmaf(w1, x1, acc);
        acc = fmaf(w2, x2, acc); acc = fmaf(w3, x3, acc);
        wsum += (w0 + w1) + (w2 + w3);
    }
    for (; p < p1; ++p) {
        int s = csr_src[p];
        float v = a2s[s] + ad; v = v > 0.f ? v : NEG * v;
        float w = __expf(v);
        acc = fmaf(w, __half2float(hw2h[(size_t)s * OUT_CH + o]), acc);
        wsum += w;
    }
    out[(size_t)d * OUT_CH + o] = acc / (wsum + 1e-16f) + b2[o];
}

extern "C" void kernel_launch(void* const* d_in, const int* in_sizes, int n_in,
                              void* d_out, int out_size, void* d_ws, size_t ws_size,
                              hipStream_t stream) {
    const float* x   = (const float*)d_in[0];
    const int*   ei  = (const int*)d_in[1];     // int32 (JAX x64 off)
    const float* W1  = (const float*)d_in[2];
    const float* as1 = (const float*)d_in[3];
    const float* ad1 = (const float*)d_in[4];
    const float* b1  = (const float*)d_in[5];
    const float* W2  = (const float*)d_in[6];
    const float* as2 = (const float*)d_in[7];
    const float* ad2 = (const float*)d_in[8];
    const float* b2  = (const float*)d_in[9];
    float* out = (float*)d_out;
    float* ws  = (float*)d_ws;

    // workspace layout (float offsets); peak ~11.8M floats = 47.2 MB
    __half* xwh   = (__half*)ws;               // 6.4M halves; dead after gather1
    __half* hw2h  = (__half*)ws;               // reuse (written by gemm2 after gather1)
    float* agg1   = ws + 3200000;              // 6.4M floats
    float* a1s    = ws + 9600000;              // 200,000 ; a2s reuses
    float* a1d    = ws + 9800000;              // 200,000 ; a2d reuses
    float* a2s    = a1s;
    float* a2d    = a1d;
    int*   deg    = (int*)(ws + 10000000);     // 50,000
    int*   rowptr = (int*)(ws + 10050000);     // 50,016
    int*   parts  = (int*)(ws + 10100016);     // 256
    int*   csr_src= (int*)(ws + 10100272);     // 850,000
    int*   idx    = (int*)(ws + 10950272);     // 850,000 -> end 11,800,272

    hipMemsetAsync(deg, 0, (size_t)N_NODES * sizeof(int), stream);

    gemm1_fused<<<GEMM_BLOCKS + FILL_BLOCKS, 256, 0, stream>>>(
        x, W1, as1, ad1, ei, xwh, a1s, a1d, deg, idx);

    scan_s1  <<<NCHUNK, 256, 0, stream>>>(deg, rowptr, parts);
    scan_s2  <<<1, 256, 0, stream>>>(parts);
    scan_s3  <<<(N_NODES + 255) / 256, 256, 0, stream>>>(rowptr, parts);
    place_csr<<<(ETOT + 255) / 256, 256, 0, stream>>>(ei, idx, rowptr, csr_src);

    gather1  <<<(N_NODES + 3) / 4, 256, 0, stream>>>(rowptr, csr_src, a1s, a1d, xwh, agg1);

    gemm2_tiled<<<(N_NODES + 31) / 32, 256, 0, stream>>>(agg1, b1, W2, as2, ad2, hw2h, a2s, a2d);
    gather2  <<<(N_NODES + 7) / 8, 256, 0, stream>>>(rowptr, csr_src, a2s, a2d, hw2h, b2, out);
}

// Round 9
// 178.128 us; speedup vs baseline: 2.7918x; 2.7918x over previous
//
#include <hip/hip_runtime.h>
#include <hip/hip_fp16.h>

#define N_NODES 50000
#define E_EDGES 800000
#define ETOT (E_EDGES + N_NODES)   // self-loops appended
#define IN_CH 128
#define HH 128                     // HEADS*HID
#define HEADS 4
#define HID 32
#define OUT_CH 32
#define NEG 0.2f

#define GEMM_BLOCKS ((N_NODES + 127) / 128)   // 391
#define FILL_BLOCKS ((ETOT + 1023) / 1024)    // 831
#define XP 132                                // padded LDS row stride

// ===== fused: [blocks 0..390] xw1 = x@W1 + att dots ; [391..] edge-rank atomic pass =====
__global__ __launch_bounds__(256, 2) void gemm1_fused(const float* __restrict__ x,
                                                      const float* __restrict__ W1,
                                                      const float* __restrict__ att_s,
                                                      const float* __restrict__ att_d,
                                                      const int* __restrict__ ei,
                                                      __half* __restrict__ xwh,
                                                      float* __restrict__ a1s,
                                                      float* __restrict__ a1d,
                                                      int* __restrict__ deg,
                                                      int* __restrict__ idx) {
    __shared__ float Xs[32][XP];
    __shared__ float Ws[32][XP];
    int t = threadIdx.x;

    if (blockIdx.x >= GEMM_BLOCKS) {
        // ---------- edge-rank pass: idx[e] = rank of e within its dst group ----------
        int base = (blockIdx.x - GEMM_BLOCKS) * 1024 + t;
#pragma unroll
        for (int q = 0; q < 4; ++q) {
            int e = base + q * 256;
            if (e < ETOT) {
                int d = (e < E_EDGES) ? ei[E_EDGES + e] : e - E_EDGES;
                idx[e] = atomicAdd(deg + d, 1);
            }
        }
        return;
    }

    // ---------- GEMM part: 128x128 tile, BK=32, 8x8 micro-tile ----------
    int tx = t & 15, ty = t >> 4;
    int row0 = blockIdx.x * 128;
    float acc[8][8] = {};

    for (int k0 = 0; k0 < IN_CH; k0 += 32) {
#pragma unroll
        for (int p = 0; p < 4; ++p) {
            int i2 = t + p * 256;
            int kk = i2 >> 5, c4 = i2 & 31;
            float4 v = *(const float4*)&W1[(size_t)(k0 + kk) * HH + c4 * 4];
            *(float4*)&Ws[kk][c4 * 4] = v;
        }
#pragma unroll
        for (int p = 0; p < 4; ++p) {
            int i2 = t + p * 256;
            int rr = i2 >> 3, c4 = i2 & 7;
            int row = row0 + rr;
            float4 v = make_float4(0.f, 0.f, 0.f, 0.f);
            if (row < N_NODES) v = *(const float4*)&x[(size_t)row * IN_CH + k0 + c4 * 4];
            Xs[c4 * 4 + 0][rr] = v.x;
            Xs[c4 * 4 + 1][rr] = v.y;
            Xs[c4 * 4 + 2][rr] = v.z;
            Xs[c4 * 4 + 3][rr] = v.w;
        }
        __syncthreads();
#pragma unroll 8
        for (int kk = 0; kk < 32; ++kk) {
            float4 xa0 = *(const float4*)&Xs[kk][ty * 4];
            float4 xa1 = *(const float4*)&Xs[kk][ty * 4 + 64];
            float4 wb0 = *(const float4*)&Ws[kk][tx * 4];
            float4 wb1 = *(const float4*)&Ws[kk][tx * 4 + 64];
            float xa[8] = {xa0.x, xa0.y, xa0.z, xa0.w, xa1.x, xa1.y, xa1.z, xa1.w};
            float wb[8] = {wb0.x, wb0.y, wb0.z, wb0.w, wb1.x, wb1.y, wb1.z, wb1.w};
#pragma unroll
            for (int i = 0; i < 8; ++i)
#pragma unroll
                for (int j = 0; j < 8; ++j)
                    acc[i][j] = fmaf(xa[i], wb[j], acc[i][j]);
        }
        __syncthreads();
    }

    float asr[8], adr[8];
#pragma unroll
    for (int j = 0; j < 8; ++j) {
        int col = tx * 4 + (j & 3) + ((j >> 2) << 6);
        asr[j] = att_s[col];
        adr[j] = att_d[col];
    }
    int hA = tx >> 3;

#pragma unroll
    for (int i = 0; i < 8; ++i) {
        int row = row0 + ty * 4 + (i < 4 ? i : 60 + i);
        if (row < N_NODES) {
            union { __half2 h2; unsigned u; } c0, c1, c2, c3;
            c0.h2 = __floats2half2_rn(acc[i][0], acc[i][1]);
            c1.h2 = __floats2half2_rn(acc[i][2], acc[i][3]);
            c2.h2 = __floats2half2_rn(acc[i][4], acc[i][5]);
            c3.h2 = __floats2half2_rn(acc[i][6], acc[i][7]);
            *(uint2*)&xwh[(size_t)row * HH + tx * 4]      = make_uint2(c0.u, c1.u);
            *(uint2*)&xwh[(size_t)row * HH + tx * 4 + 64] = make_uint2(c2.u, c3.u);
        }
        float psA = 0.f, pdA = 0.f, psB = 0.f, pdB = 0.f;
#pragma unroll
        for (int j = 0; j < 4; ++j) {
            psA = fmaf(acc[i][j], asr[j], psA);
            pdA = fmaf(acc[i][j], adr[j], pdA);
            psB = fmaf(acc[i][j + 4], asr[j + 4], psB);
            pdB = fmaf(acc[i][j + 4], adr[j + 4], pdB);
        }
#pragma unroll
        for (int off = 1; off < 8; off <<= 1) {
            psA += __shfl_xor(psA, off, 16);
            pdA += __shfl_xor(pdA, off, 16);
            psB += __shfl_xor(psB, off, 16);
            pdB += __shfl_xor(pdB, off, 16);
        }
        if ((tx & 7) == 0 && row < N_NODES) {
            a1s[row * 4 + hA]     = psA;
            a1d[row * 4 + hA]     = pdA;
            a1s[row * 4 + hA + 2] = psB;
            a1d[row * 4 + hA + 2] = pdB;
        }
    }
}

// ================= scan (rowptr from deg) =================
__device__ __forceinline__ int block_incl_scan(int v, int t) {
    for (int off = 1; off < 64; off <<= 1) {
        int n = __shfl_up(v, off, 64);
        if ((t & 63) >= off) v += n;
    }
    __shared__ int wsum[4];
    if ((t & 63) == 63) wsum[t >> 6] = v;
    __syncthreads();
    int w = t >> 6;
    if (w > 0) {
        int add = 0;
        for (int k = 0; k < w; ++k) add += wsum[k];
        v += add;
    }
    __syncthreads();
    return v;
}

#define NCHUNK ((N_NODES + 255) / 256)   // 196

__global__ void scan_s1(const int* __restrict__ deg, int* __restrict__ rowptr,
                        int* __restrict__ partials) {
    int t = threadIdx.x;
    int i = blockIdx.x * 256 + t;
    int v = (i < N_NODES) ? deg[i] : 0;
    int s = block_incl_scan(v, t);
    if (i < N_NODES) rowptr[i + 1] = s;
    if (t == 255) partials[blockIdx.x] = s;
}

__global__ void scan_s2(int* __restrict__ partials) {
    int t = threadIdx.x;
    int v = (t < NCHUNK) ? partials[t] : 0;
    int s = block_incl_scan(v, t);
    if (t < NCHUNK) partials[t] = s;
}

__global__ void scan_s3(int* __restrict__ rowptr, const int* __restrict__ partials) {
    int i = blockIdx.x * blockDim.x + threadIdx.x;
    if (i == 0) rowptr[0] = 0;
    if (i < N_NODES) {
        int c = i >> 8;
        if (c > 0) rowptr[i + 1] += partials[c - 1];
    }
}

// ================= place: csr_src[rowptr[d]+idx[e]] = s (no atomics) =================
__global__ void place_csr(const int* __restrict__ ei, const int* __restrict__ idx,
                          const int* __restrict__ rowptr, int* __restrict__ csr_src) {
    int e = blockIdx.x * blockDim.x + threadIdx.x;
    if (e >= ETOT) return;
    int s, d;
    if (e < E_EDGES) { s = ei[e]; d = ei[E_EDGES + e]; }
    else { s = e - E_EDGES; d = s; }
    csr_src[rowptr[d] + idx[e]] = s;
}

// ========== layer-1 gather-aggregate, fused denominator, 4-edge ILP ==========
__global__ void gather1(const int* __restrict__ rowptr, const int* __restrict__ csr_src,
                        const float* __restrict__ a1s, const float* __restrict__ a1d,
                        const __half* __restrict__ xwh, float* __restrict__ agg) {
    int t = threadIdx.x;
    int d = blockIdx.x * 4 + (t >> 6);   // one 64-lane wave per node
    if (d >= N_NODES) return;
    int l = t & 63;                       // channels 2l, 2l+1; head = l>>4
    int h = l >> 4;
    float ad = a1d[d * 4 + h];
    int p0 = rowptr[d], p1 = rowptr[d + 1];
    float acc0 = 0.f, acc1 = 0.f, wsum = 0.f;
    int p = p0;
    for (; p + 3 < p1; p += 4) {
        int s0 = csr_src[p], s1 = csr_src[p + 1], s2 = csr_src[p + 2], s3 = csr_src[p + 3];
        float v0 = a1s[s0 * 4 + h] + ad; v0 = v0 > 0.f ? v0 : NEG * v0;
        float v1 = a1s[s1 * 4 + h] + ad; v1 = v1 > 0.f ? v1 : NEG * v1;
        float v2 = a1s[s2 * 4 + h] + ad; v2 = v2 > 0.f ? v2 : NEG * v2;
        float v3 = a1s[s3 * 4 + h] + ad; v3 = v3 > 0.f ? v3 : NEG * v3;
        float w0 = __expf(v0), w1 = __expf(v1), w2 = __expf(v2), w3 = __expf(v3);
        float2 f0 = __half22float2(*(const __half2*)&xwh[(size_t)s0 * HH + 2 * l]);
        float2 f1 = __half22float2(*(const __half2*)&xwh[(size_t)s1 * HH + 2 * l]);
        float2 f2 = __half22float2(*(const __half2*)&xwh[(size_t)s2 * HH + 2 * l]);
        float2 f3 = __half22float2(*(const __half2*)&xwh[(size_t)s3 * HH + 2 * l]);
        acc0 = fmaf(w0, f0.x, acc0); acc1 = fmaf(w0, f0.y, acc1);
        acc0 = fmaf(w1, f1.x, acc0); acc1 = fmaf(w1, f1.y, acc1);
        acc0 = fmaf(w2, f2.x, acc0); acc1 = fmaf(w2, f2.y, acc1);
        acc0 = fmaf(w3, f3.x, acc0); acc1 = fmaf(w3, f3.y, acc1);
        wsum += (w0 + w1) + (w2 + w3);
    }
    for (; p < p1; ++p) {
        int s = csr_src[p];
        float v = a1s[s * 4 + h] + ad; v = v > 0.f ? v : NEG * v;
        float w = __expf(v);
        float2 f = __half22float2(*(const __half2*)&xwh[(size_t)s * HH + 2 * l]);
        acc0 = fmaf(w, f.x, acc0); acc1 = fmaf(w, f.y, acc1);
        wsum += w;
    }
    float r = 1.f / (wsum + 1e-16f);
    *(float2*)&agg[(size_t)d * HH + 2 * l] = make_float2(acc0 * r, acc1 * r);
}

// ====== layer-2 GEMM (round-7 proven): h = elu(agg+b1); hw2 = h @ W2 (fp16) ======
__global__ void gemm2_kernel(const float* __restrict__ agg1,
                             const float* __restrict__ b1,
                             const float* __restrict__ W2,
                             const float* __restrict__ att_s,
                             const float* __restrict__ att_d,
                             __half* __restrict__ hw2h,
                             float* __restrict__ a2s,
                             float* __restrict__ a2d) {
    __shared__ float Wl[HH * OUT_CH];  // 16 KiB
    __shared__ float hs[8][HH];        // 4 KiB
    int t = threadIdx.x;
    for (int i = t; i < HH * OUT_CH; i += 256) Wl[i] = W2[i];
    __syncthreads();
    int nChunks = (N_NODES + 7) / 8;
    for (int ch = blockIdx.x; ch < nChunks; ch += gridDim.x) {
        int row0 = ch * 8;
        __syncthreads();
        for (int i = t; i < 8 * HH; i += 256) {
            int rr = i >> 7, jj = i & 127;
            int row = row0 + rr;
            if (row < N_NODES) {
                float v = agg1[(size_t)row * HH + jj] + b1[jj];
                hs[rr][jj] = v > 0.f ? v : (__expf(v) - 1.f);   // ELU
            }
        }
        __syncthreads();
        int r = t >> 5, o = t & 31;
        int row = row0 + r;
        if (row < N_NODES) {
            float acc = 0.f;
#pragma unroll 4
            for (int jj = 0; jj < HH; ++jj) acc = fmaf(hs[r][jj], Wl[jj * OUT_CH + o], acc);
            hw2h[(size_t)row * OUT_CH + o] = __float2half_rn(acc);
            float ps = acc * att_s[o], pd = acc * att_d[o];
            for (int off = 16; off; off >>= 1) {
                ps += __shfl_down(ps, off, 32);
                pd += __shfl_down(pd, off, 32);
            }
            if (o == 0) { a2s[row] = ps; a2d[row] = pd; }
        }
    }
}

// ========== layer-2 gather-aggregate, fused denominator, 4-edge ILP ==========
__global__ void gather2(const int* __restrict__ rowptr, const int* __restrict__ csr_src,
                        const float* __restrict__ a2s, const float* __restrict__ a2d,
                        const __half* __restrict__ hw2h, const float* __restrict__ b2,
                        float* __restrict__ out) {
    int t = threadIdx.x;
    int d = blockIdx.x * 8 + (t >> 5);   // 32 lanes per node
    if (d >= N_NODES) return;
    int o = t & 31;
    float ad = a2d[d];
    int p0 = rowptr[d], p1 = rowptr[d + 1];
    float acc = 0.f, wsum = 0.f;
    int p = p0;
    for (; p + 3 < p1; p += 4) {
        int s0 = csr_src[p], s1 = csr_src[p + 1], s2 = csr_src[p + 2], s3 = csr_src[p + 3];
        float v0 = a2s[s0] + ad; v0 = v0 > 0.f ? v0 : NEG * v0;
        float v1 = a2s[s1] + ad; v1 = v1 > 0.f ? v1 : NEG * v1;
        float v2 = a2s[s2] + ad; v2 = v2 > 0.f ? v2 : NEG * v2;
        float v3 = a2s[s3] + ad; v3 = v3 > 0.f ? v3 : NEG * v3;
        float w0 = __expf(v0), w1 = __expf(v1), w2 = __expf(v2), w3 = __expf(v3);
        float x0 = __half2float(hw2h[(size_t)s0 * OUT_CH + o]);
        float x1 = __half2float(hw2h[(size_t)s1 * OUT_CH + o]);
        float x2 = __half2float(hw2h[(size_t)s2 * OUT_CH + o]);
        float x3 = __half2float(hw2h[(size_t)s3 * OUT_CH + o]);
        acc = fmaf(w0, x0, acc); acc = fmaf(w1, x1, acc);
        acc = fmaf(w2, x2, acc); acc = fmaf(w3, x3, acc);
        wsum += (w0 + w1) + (w2 + w3);
    }
    for (; p < p1; ++p) {
        int s = csr_src[p];
        float v = a2s[s] + ad; v = v > 0.f ? v : NEG * v;
        float w = __expf(v);
        acc = fmaf(w, __half2float(hw2h[(size_t)s * OUT_CH + o]), acc);
        wsum += w;
    }
    out[(size_t)d * OUT_CH + o] = acc / (wsum + 1e-16f) + b2[o];
}

extern "C" void kernel_launch(void* const* d_in, const int* in_sizes, int n_in,
                              void* d_out, int out_size, void* d_ws, size_t ws_size,
                              hipStream_t stream) {
    const float* x   = (const float*)d_in[0];
    const int*   ei  = (const int*)d_in[1];     // int32 (JAX x64 off)
    const float* W1  = (const float*)d_in[2];
    const float* as1 = (const float*)d_in[3];
    const float* ad1 = (const float*)d_in[4];
    const float* b1  = (const float*)d_in[5];
    const float* W2  = (const float*)d_in[6];
    const float* as2 = (const float*)d_in[7];
    const float* ad2 = (const float*)d_in[8];
    const float* b2  = (const float*)d_in[9];
    float* out = (float*)d_out;
    float* ws  = (float*)d_ws;

    // workspace layout (float offsets); peak ~11.8M floats = 47.2 MB
    __half* xwh   = (__half*)ws;               // 6.4M halves; dead after gather1
    __half* hw2h  = (__half*)ws;               // reuse (written by gemm2 after gather1)
    float* agg1   = ws + 3200000;              // 6.4M floats
    float* a1s    = ws + 9600000;              // 200,000 ; a2s reuses
    float* a1d    = ws + 9800000;              // 200,000 ; a2d reuses
    float* a2s    = a1s;
    float* a2d    = a1d;
    int*   deg    = (int*)(ws + 10000000);     // 50,000
    int*   rowptr = (int*)(ws + 10050000);     // 50,016
    int*   parts  = (int*)(ws + 10100016);     // 256
    int*   csr_src= (int*)(ws + 10100272);     // 850,000
    int*   idx    = (int*)(ws + 10950272);     // 850,000 -> end 11,800,272

    hipMemsetAsync(deg, 0, (size_t)N_NODES * sizeof(int), stream);

    gemm1_fused<<<GEMM_BLOCKS + FILL_BLOCKS, 256, 0, stream>>>(
        x, W1, as1, ad1, ei, xwh, a1s, a1d, deg, idx);

    scan_s1  <<<NCHUNK, 256, 0, stream>>>(deg, rowptr, parts);
    scan_s2  <<<1, 256, 0, stream>>>(parts);
    scan_s3  <<<(N_NODES + 255) / 256, 256, 0, stream>>>(rowptr, parts);
    place_csr<<<(ETOT + 255) / 256, 256, 0, stream>>>(ei, idx, rowptr, csr_src);

    gather1  <<<(N_NODES + 3) / 4, 256, 0, stream>>>(rowptr, csr_src, a1s, a1d, xwh, agg1);

    gemm2_kernel<<<2048, 256, 0, stream>>>(agg1, b1, W2, as2, ad2, hw2h, a2s, a2d);
    gather2  <<<(N_NODES + 7) / 8, 256, 0, stream>>>(rowptr, csr_src, a2s, a2d, hw2h, b2, out);
}

// Round 10
// 172.843 us; speedup vs baseline: 2.8772x; 1.0306x over previous
//
#include <hip/hip_runtime.h>
#include <hip/hip_fp16.h>

#define N_NODES 50000
#define E_EDGES 800000
#define ETOT (E_EDGES + N_NODES)   // self-loops appended
#define IN_CH 128
#define HH 128                     // HEADS*HID
#define HEADS 4
#define HID 32
#define OUT_CH 32
#define NEG 0.2f

#define GEMM_BLOCKS ((N_NODES + 127) / 128)   // 391
#define FILL_BLOCKS ((ETOT + 1023) / 1024)    // 831
#define XP 132                                // padded LDS row stride

// ===== fused: [blocks 0..390] xw1 = x@W1 + att dots ; [391..] edge-rank atomic pass =====
__global__ __launch_bounds__(256, 2) void gemm1_fused(const float* __restrict__ x,
                                                      const float* __restrict__ W1,
                                                      const float* __restrict__ att_s,
                                                      const float* __restrict__ att_d,
                                                      const int* __restrict__ ei,
                                                      __half* __restrict__ xwh,
                                                      float* __restrict__ a1s,
                                                      float* __restrict__ a1d,
                                                      int* __restrict__ deg,
                                                      int* __restrict__ idx) {
    __shared__ float Xs[32][XP];
    __shared__ float Ws[32][XP];
    int t = threadIdx.x;

    if (blockIdx.x >= GEMM_BLOCKS) {
        // ---------- edge-rank pass: idx[e] = rank of e within its dst group ----------
        int base = (blockIdx.x - GEMM_BLOCKS) * 1024 + t;
#pragma unroll
        for (int q = 0; q < 4; ++q) {
            int e = base + q * 256;
            if (e < ETOT) {
                int d = (e < E_EDGES) ? ei[E_EDGES + e] : e - E_EDGES;
                idx[e] = atomicAdd(deg + d, 1);
            }
        }
        return;
    }

    // ---------- GEMM part: 128x128 tile, BK=32, 8x8 micro-tile ----------
    int tx = t & 15, ty = t >> 4;
    int row0 = blockIdx.x * 128;
    float acc[8][8] = {};

    for (int k0 = 0; k0 < IN_CH; k0 += 32) {
#pragma unroll
        for (int p = 0; p < 4; ++p) {
            int i2 = t + p * 256;
            int kk = i2 >> 5, c4 = i2 & 31;
            float4 v = *(const float4*)&W1[(size_t)(k0 + kk) * HH + c4 * 4];
            *(float4*)&Ws[kk][c4 * 4] = v;
        }
#pragma unroll
        for (int p = 0; p < 4; ++p) {
            int i2 = t + p * 256;
            int rr = i2 >> 3, c4 = i2 & 7;
            int row = row0 + rr;
            float4 v = make_float4(0.f, 0.f, 0.f, 0.f);
            if (row < N_NODES) v = *(const float4*)&x[(size_t)row * IN_CH + k0 + c4 * 4];
            Xs[c4 * 4 + 0][rr] = v.x;
            Xs[c4 * 4 + 1][rr] = v.y;
            Xs[c4 * 4 + 2][rr] = v.z;
            Xs[c4 * 4 + 3][rr] = v.w;
        }
        __syncthreads();
#pragma unroll 8
        for (int kk = 0; kk < 32; ++kk) {
            float4 xa0 = *(const float4*)&Xs[kk][ty * 4];
            float4 xa1 = *(const float4*)&Xs[kk][ty * 4 + 64];
            float4 wb0 = *(const float4*)&Ws[kk][tx * 4];
            float4 wb1 = *(const float4*)&Ws[kk][tx * 4 + 64];
            float xa[8] = {xa0.x, xa0.y, xa0.z, xa0.w, xa1.x, xa1.y, xa1.z, xa1.w};
            float wb[8] = {wb0.x, wb0.y, wb0.z, wb0.w, wb1.x, wb1.y, wb1.z, wb1.w};
#pragma unroll
            for (int i = 0; i < 8; ++i)
#pragma unroll
                for (int j = 0; j < 8; ++j)
                    acc[i][j] = fmaf(xa[i], wb[j], acc[i][j]);
        }
        __syncthreads();
    }

    float asr[8], adr[8];
#pragma unroll
    for (int j = 0; j < 8; ++j) {
        int col = tx * 4 + (j & 3) + ((j >> 2) << 6);
        asr[j] = att_s[col];
        adr[j] = att_d[col];
    }
    int hA = tx >> 3;

#pragma unroll
    for (int i = 0; i < 8; ++i) {
        int row = row0 + ty * 4 + (i < 4 ? i : 60 + i);
        if (row < N_NODES) {
            union { __half2 h2; unsigned u; } c0, c1, c2, c3;
            c0.h2 = __floats2half2_rn(acc[i][0], acc[i][1]);
            c1.h2 = __floats2half2_rn(acc[i][2], acc[i][3]);
            c2.h2 = __floats2half2_rn(acc[i][4], acc[i][5]);
            c3.h2 = __floats2half2_rn(acc[i][6], acc[i][7]);
            *(uint2*)&xwh[(size_t)row * HH + tx * 4]      = make_uint2(c0.u, c1.u);
            *(uint2*)&xwh[(size_t)row * HH + tx * 4 + 64] = make_uint2(c2.u, c3.u);
        }
        float psA = 0.f, pdA = 0.f, psB = 0.f, pdB = 0.f;
#pragma unroll
        for (int j = 0; j < 4; ++j) {
            psA = fmaf(acc[i][j], asr[j], psA);
            pdA = fmaf(acc[i][j], adr[j], pdA);
            psB = fmaf(acc[i][j + 4], asr[j + 4], psB);
            pdB = fmaf(acc[i][j + 4], adr[j + 4], pdB);
        }
#pragma unroll
        for (int off = 1; off < 8; off <<= 1) {
            psA += __shfl_xor(psA, off, 16);
            pdA += __shfl_xor(pdA, off, 16);
            psB += __shfl_xor(psB, off, 16);
            pdB += __shfl_xor(pdB, off, 16);
        }
        if ((tx & 7) == 0 && row < N_NODES) {
            a1s[row * 4 + hA]     = psA;
            a1d[row * 4 + hA]     = pdA;
            a1s[row * 4 + hA + 2] = psB;
            a1d[row * 4 + hA + 2] = pdB;
        }
    }
}

// ================= scan (rowptr from deg) =================
__device__ __forceinline__ int block_incl_scan(int v, int t) {
    for (int off = 1; off < 64; off <<= 1) {
        int n = __shfl_up(v, off, 64);
        if ((t & 63) >= off) v += n;
    }
    __shared__ int wsum[4];
    if ((t & 63) == 63) wsum[t >> 6] = v;
    __syncthreads();
    int w = t >> 6;
    if (w > 0) {
        int add = 0;
        for (int k = 0; k < w; ++k) add += wsum[k];
        v += add;
    }
    __syncthreads();
    return v;
}

#define NCHUNK ((N_NODES + 255) / 256)   // 196

__global__ void scan_s1(const int* __restrict__ deg, int* __restrict__ rowptr,
                        int* __restrict__ partials) {
    int t = threadIdx.x;
    int i = blockIdx.x * 256 + t;
    int v = (i < N_NODES) ? deg[i] : 0;
    int s = block_incl_scan(v, t);
    if (i < N_NODES) rowptr[i + 1] = s;
    if (t == 255) partials[blockIdx.x] = s;
}

__global__ void scan_s2(int* __restrict__ partials) {
    int t = threadIdx.x;
    int v = (t < NCHUNK) ? partials[t] : 0;
    int s = block_incl_scan(v, t);
    if (t < NCHUNK) partials[t] = s;
}

__global__ void scan_s3(int* __restrict__ rowptr, const int* __restrict__ partials) {
    int i = blockIdx.x * blockDim.x + threadIdx.x;
    if (i == 0) rowptr[0] = 0;
    if (i < N_NODES) {
        int c = i >> 8;
        if (c > 0) rowptr[i + 1] += partials[c - 1];
    }
}

// ================= place: csr_src[rowptr[d]+idx[e]] = s (no atomics) =================
__global__ void place_csr(const int* __restrict__ ei, const int* __restrict__ idx,
                          const int* __restrict__ rowptr, int* __restrict__ csr_src) {
    int e = blockIdx.x * blockDim.x + threadIdx.x;
    if (e >= ETOT) return;
    int s, d;
    if (e < E_EDGES) { s = ei[e]; d = ei[E_EDGES + e]; }
    else { s = e - E_EDGES; d = s; }
    csr_src[rowptr[d] + idx[e]] = s;
}

// ========== layer-1 gather + fused denominator + FUSED gemm2/att-dots ==========
// One 64-lane wave per node. After the edge loop the wave owns agg[d] in regs;
// elu(+b1) -> LDS h row -> dot with LDS W2 -> hw2h + a2s/a2d. No agg1 round trip.
// N_NODES % 4 == 0 so every block has 4 full nodes (no early return vs barrier).
__global__ void gather1_g2(const int* __restrict__ rowptr, const int* __restrict__ csr_src,
                           const float* __restrict__ a1s, const float* __restrict__ a1d,
                           const __half* __restrict__ xwh,
                           const float* __restrict__ b1, const float* __restrict__ W2,
                           const float* __restrict__ att_s2, const float* __restrict__ att_d2,
                           __half* __restrict__ hw2h,
                           float* __restrict__ a2s, float* __restrict__ a2d) {
    __shared__ float Wl[HH * OUT_CH];   // W2 [j*32+o], 16 KiB; lane o -> bank o
    __shared__ float hs[4][HH];         // per-wave h row, 2 KiB
    int t = threadIdx.x;
    for (int i = t; i < HH * OUT_CH; i += 256) Wl[i] = W2[i];
    __syncthreads();

    int wid = t >> 6;
    int d = blockIdx.x * 4 + wid;
    int l = t & 63;                      // channels 2l, 2l+1; head = l>>4
    int h = l >> 4;
    float ad = a1d[d * 4 + h];
    int p0 = rowptr[d], p1 = rowptr[d + 1];
    float acc0 = 0.f, acc1 = 0.f, wsum = 0.f;
    int p = p0;
    for (; p + 3 < p1; p += 4) {
        int s0 = csr_src[p], s1 = csr_src[p + 1], s2 = csr_src[p + 2], s3 = csr_src[p + 3];
        float v0 = a1s[s0 * 4 + h] + ad; v0 = v0 > 0.f ? v0 : NEG * v0;
        float v1 = a1s[s1 * 4 + h] + ad; v1 = v1 > 0.f ? v1 : NEG * v1;
        float v2 = a1s[s2 * 4 + h] + ad; v2 = v2 > 0.f ? v2 : NEG * v2;
        float v3 = a1s[s3 * 4 + h] + ad; v3 = v3 > 0.f ? v3 : NEG * v3;
        float w0 = __expf(v0), w1 = __expf(v1), w2 = __expf(v2), w3 = __expf(v3);
        float2 f0 = __half22float2(*(const __half2*)&xwh[(size_t)s0 * HH + 2 * l]);
        float2 f1 = __half22float2(*(const __half2*)&xwh[(size_t)s1 * HH + 2 * l]);
        float2 f2 = __half22float2(*(const __half2*)&xwh[(size_t)s2 * HH + 2 * l]);
        float2 f3 = __half22float2(*(const __half2*)&xwh[(size_t)s3 * HH + 2 * l]);
        acc0 = fmaf(w0, f0.x, acc0); acc1 = fmaf(w0, f0.y, acc1);
        acc0 = fmaf(w1, f1.x, acc0); acc1 = fmaf(w1, f1.y, acc1);
        acc0 = fmaf(w2, f2.x, acc0); acc1 = fmaf(w2, f2.y, acc1);
        acc0 = fmaf(w3, f3.x, acc0); acc1 = fmaf(w3, f3.y, acc1);
        wsum += (w0 + w1) + (w2 + w3);
    }
    for (; p < p1; ++p) {
        int s = csr_src[p];
        float v = a1s[s * 4 + h] + ad; v = v > 0.f ? v : NEG * v;
        float w = __expf(v);
        float2 f = __half22float2(*(const __half2*)&xwh[(size_t)s * HH + 2 * l]);
        acc0 = fmaf(w, f.x, acc0); acc1 = fmaf(w, f.y, acc1);
        wsum += w;
    }
    float r = 1.f / (wsum + 1e-16f);
    float2 bv = *(const float2*)&b1[2 * l];
    float h0 = acc0 * r + bv.x;
    float h1 = acc1 * r + bv.y;
    h0 = h0 > 0.f ? h0 : (__expf(h0) - 1.f);     // ELU
    h1 = h1 > 0.f ? h1 : (__expf(h1) - 1.f);
    *(float2*)&hs[wid][2 * l] = make_float2(h0, h1);
    // same-wave LDS write->read: lgkmcnt ordering enforced by compiler (no barrier;
    // each wave reads only its own hs row)

    // ---- gemm2 part: out[o] = sum_j h[j]*W2[j][o]; lane = (o = l&31, half = l>>5) ----
    int o = l & 31, half = l >> 5;
    const float* hrow = &hs[wid][half * 64];
    const float* wcol = &Wl[half * 64 * OUT_CH + o];
    float acc = 0.f;
#pragma unroll 8
    for (int j = 0; j < 64; ++j) acc = fmaf(hrow[j], wcol[j * OUT_CH], acc);
    acc += __shfl_xor(acc, 32, 64);               // combine halves -> full dot in all lanes

    if (half == 0) hw2h[(size_t)d * OUT_CH + o] = __float2half_rn(acc);

    float ps = acc * att_s2[o], pd = acc * att_d2[o];
#pragma unroll
    for (int off = 16; off; off >>= 1) {
        ps += __shfl_xor(ps, off, 32);
        pd += __shfl_xor(pd, off, 32);
    }
    if (l == 0) { a2s[d] = ps; a2d[d] = pd; }
}

// ========== layer-2 gather-aggregate, fused denominator, 4-edge ILP ==========
__global__ void gather2(const int* __restrict__ rowptr, const int* __restrict__ csr_src,
                        const float* __restrict__ a2s, const float* __restrict__ a2d,
                        const __half* __restrict__ hw2h, const float* __restrict__ b2,
                        float* __restrict__ out) {
    int t = threadIdx.x;
    int d = blockIdx.x * 8 + (t >> 5);   // 32 lanes per node
    if (d >= N_NODES) return;
    int o = t & 31;
    float ad = a2d[d];
    int p0 = rowptr[d], p1 = rowptr[d + 1];
    float acc = 0.f, wsum = 0.f;
    int p = p0;
    for (; p + 3 < p1; p += 4) {
        int s0 = csr_src[p], s1 = csr_src[p + 1], s2 = csr_src[p + 2], s3 = csr_src[p + 3];
        float v0 = a2s[s0] + ad; v0 = v0 > 0.f ? v0 : NEG * v0;
        float v1 = a2s[s1] + ad; v1 = v1 > 0.f ? v1 : NEG * v1;
        float v2 = a2s[s2] + ad; v2 = v2 > 0.f ? v2 : NEG * v2;
        float v3 = a2s[s3] + ad; v3 = v3 > 0.f ? v3 : NEG * v3;
        float w0 = __expf(v0), w1 = __expf(v1), w2 = __expf(v2), w3 = __expf(v3);
        float x0 = __half2float(hw2h[(size_t)s0 * OUT_CH + o]);
        float x1 = __half2float(hw2h[(size_t)s1 * OUT_CH + o]);
        float x2 = __half2float(hw2h[(size_t)s2 * OUT_CH + o]);
        float x3 = __half2float(hw2h[(size_t)s3 * OUT_CH + o]);
        acc = fmaf(w0, x0, acc); acc = fmaf(w1, x1, acc);
        acc = fmaf(w2, x2, acc); acc = fmaf(w3, x3, acc);
        wsum += (w0 + w1) + (w2 + w3);
    }
    for (; p < p1; ++p) {
        int s = csr_src[p];
        float v = a2s[s] + ad; v = v > 0.f ? v : NEG * v;
        float w = __expf(v);
        acc = fmaf(w, __half2float(hw2h[(size_t)s * OUT_CH + o]), acc);
        wsum += w;
    }
    out[(size_t)d * OUT_CH + o] = acc / (wsum + 1e-16f) + b2[o];
}

extern "C" void kernel_launch(void* const* d_in, const int* in_sizes, int n_in,
                              void* d_out, int out_size, void* d_ws, size_t ws_size,
                              hipStream_t stream) {
    const float* x   = (const float*)d_in[0];
    const int*   ei  = (const int*)d_in[1];     // int32 (JAX x64 off)
    const float* W1  = (const float*)d_in[2];
    const float* as1 = (const float*)d_in[3];
    const float* ad1 = (const float*)d_in[4];
    const float* b1  = (const float*)d_in[5];
    const float* W2  = (const float*)d_in[6];
    const float* as2 = (const float*)d_in[7];
    const float* ad2 = (const float*)d_in[8];
    const float* b2  = (const float*)d_in[9];
    float* out = (float*)d_out;
    float* ws  = (float*)d_ws;

    // workspace layout (float offsets); peak 6,300,272 floats = 25.2 MB
    __half* xwh   = (__half*)ws;               // 6.4M halves (3.2M floats)
    __half* hw2h  = (__half*)(ws + 3200000);   // 1.6M halves (800K floats) — live with xwh!
    float* a1s    = ws + 4000000;              // 200,000
    float* a1d    = ws + 4200000;              // 200,000
    float* a2s    = ws + 4400000;              //  50,000
    float* a2d    = ws + 4450000;              //  50,000
    int*   deg    = (int*)(ws + 4500000);      //  50,000
    int*   rowptr = (int*)(ws + 4550000);      //  50,016
    int*   parts  = (int*)(ws + 4600016);      //     256
    int*   csr_src= (int*)(ws + 4600272);      // 850,000
    int*   idx    = (int*)(ws + 5450272);      // 850,000 -> end 6,300,272

    hipMemsetAsync(deg, 0, (size_t)N_NODES * sizeof(int), stream);

    gemm1_fused<<<GEMM_BLOCKS + FILL_BLOCKS, 256, 0, stream>>>(
        x, W1, as1, ad1, ei, xwh, a1s, a1d, deg, idx);

    scan_s1  <<<NCHUNK, 256, 0, stream>>>(deg, rowptr, parts);
    scan_s2  <<<1, 256, 0, stream>>>(parts);
    scan_s3  <<<(N_NODES + 255) / 256, 256, 0, stream>>>(rowptr, parts);
    place_csr<<<(ETOT + 255) / 256, 256, 0, stream>>>(ei, idx, rowptr, csr_src);

    gather1_g2<<<N_NODES / 4, 256, 0, stream>>>(rowptr, csr_src, a1s, a1d, xwh,
                                                b1, W2, as2, ad2, hw2h, a2s, a2d);

    gather2  <<<(N_NODES + 7) / 8, 256, 0, stream>>>(rowptr, csr_src, a2s, a2d, hw2h, b2, out);
}